// Round 2
// baseline (1313.030 us; speedup 1.0000x reference)
//
#include <hip/hip_runtime.h>
#include <math.h>

#define H 128
#define RANK 16
#define SCALING 2.0f
#define LN_EPS 1e-5f
#define TILE 32

// ---------------- degree count ----------------
__global__ void k_deg(const int* __restrict__ col, int E, int* __restrict__ deg) {
    int e = blockIdx.x * blockDim.x + threadIdx.x;
    if (e < E) atomicAdd(&deg[col[e]], 1);
}

// ---------------- dinv / rdeg ----------------
__global__ void k_dinv(const int* __restrict__ deg, int N,
                       float* __restrict__ dinv, float* __restrict__ rdeg) {
    int i = blockIdx.x * blockDim.x + threadIdx.x;
    if (i < N) {
        float d = (float)(deg[i] + 1);   // +1 self loop
        dinv[i] = rsqrtf(d);
        rdeg[i] = 1.0f / d;
    }
}

// ---------------- self-loop init: summed = dinv^2 * x ----------------
__global__ void k_selfinit(const float4* __restrict__ x4, const float* __restrict__ dinv,
                           int N, float4* __restrict__ summed4) {
    int idx = blockIdx.x * blockDim.x + threadIdx.x;  // N*32 float4s
    if (idx < N * (H / 4)) {
        int n = idx >> 5;
        float s = dinv[n];
        s = s * s;
        float4 v = x4[idx];
        v.x *= s; v.y *= s; v.z *= s; v.w *= s;
        summed4[idx] = v;
    }
}

// ---------------- edge scatter (fp32 atomics) ----------------
__global__ void k_scatter(const int* __restrict__ ei, int E, const float* __restrict__ dinv,
                          const float4* __restrict__ x4, float* summed) {
    int t = blockIdx.x * blockDim.x + threadIdx.x;
    int e = t >> 5, q = t & 31;
    if (e < E) {
        int r = ei[e];        // source
        int c = ei[E + e];    // target
        float norm = dinv[r] * dinv[c];
        float4 v = x4[r * 32 + q];
        float* dst = summed + c * H + q * 4;
        atomicAdd(dst + 0, norm * v.x);
        atomicAdd(dst + 1, norm * v.y);
        atomicAdd(dst + 2, norm * v.z);
        atomicAdd(dst + 3, norm * v.w);
    }
}

// ---------------- LoRA fold: Weff[k][h] = W[h][k] + S * sum_r A[r][k]*B[h][r] ----------------
__global__ void k_weff(const float* __restrict__ W, const float* __restrict__ A,
                       const float* __restrict__ B, float* __restrict__ Weff) {
    int idx = blockIdx.x * blockDim.x + threadIdx.x;  // H*H
    if (idx < H * H) {
        int h = idx & (H - 1);
        int k = idx >> 7;
        float s = 0.f;
        #pragma unroll
        for (int r = 0; r < RANK; ++r) s = fmaf(A[r * H + k], B[h * RANK + r], s);
        Weff[k * H + h] = W[h * H + k] + SCALING * s;
    }
}

// ---------------- fused: both GEMMs + sigmoid gate + residual + LayerNorm ----------------
__device__ __forceinline__ void fma4(float4& acc, float s, const float4& wv) {
    acc.x = fmaf(s, wv.x, acc.x);
    acc.y = fmaf(s, wv.y, acc.y);
    acc.z = fmaf(s, wv.z, acc.z);
    acc.w = fmaf(s, wv.w, acc.w);
}

__global__ __launch_bounds__(256, 2) void k_fused(
    const float* __restrict__ hidden, const float* summed, const float* __restrict__ rdeg,
    const float* __restrict__ Wm, const float* __restrict__ Wg,
    const float* __restrict__ msg_b, const float* __restrict__ gate_b,
    const float* __restrict__ gamma, const float* __restrict__ beta,
    float* out, int N) {
    __shared__ float xh[TILE * H];
    __shared__ float xm[TILE * H];
    __shared__ float wgs[32 * H];
    __shared__ float wms[32 * H];

    int t = threadIdx.x;
    int tileBase = blockIdx.x * TILE;

    // stage input tiles (hidden and summed*rdeg)
    const float4* h4 = (const float4*)(hidden + (size_t)tileBase * H);
    const float4* s4 = (const float4*)(summed + (size_t)tileBase * H);
    float4* xh4 = (float4*)xh;
    float4* xm4 = (float4*)xm;
    #pragma unroll
    for (int i = 0; i < 4; ++i) {
        int idx = t + i * 256;       // 1024 float4s = 32 rows
        int n = idx >> 5;
        int gn = tileBase + n;
        float4 hv = make_float4(0.f, 0.f, 0.f, 0.f);
        float4 sv = make_float4(0.f, 0.f, 0.f, 0.f);
        if (gn < N) {
            float rd = rdeg[gn];
            hv = h4[idx];
            sv = s4[idx];
            sv.x *= rd; sv.y *= rd; sv.z *= rd; sv.w *= rd;
        }
        xh4[idx] = hv;
        xm4[idx] = sv;
    }

    int fg = t & 31;   // feature group: features fg*4..fg*4+3
    int ng = t >> 5;   // node group: nodes ng*4..ng*4+3
    float4 accg[4], accm[4];
    #pragma unroll
    for (int n = 0; n < 4; ++n) {
        accg[n] = make_float4(0.f, 0.f, 0.f, 0.f);
        accm[n] = make_float4(0.f, 0.f, 0.f, 0.f);
    }

    for (int c = 0; c < 4; ++c) {
        __syncthreads();
        // stage 32 K-rows of each W
        const float4* wg4 = (const float4*)(Wg + c * 32 * H);
        const float4* wm4 = (const float4*)(Wm + c * 32 * H);
        #pragma unroll
        for (int i = 0; i < 4; ++i) {
            ((float4*)wgs)[t + i * 256] = wg4[t + i * 256];
            ((float4*)wms)[t + i * 256] = wm4[t + i * 256];
        }
        __syncthreads();
        #pragma unroll
        for (int kk = 0; kk < 32; kk += 4) {
            int kbase = c * 32 + kk;
            float4 xhv[4], xmv[4];
            #pragma unroll
            for (int n = 0; n < 4; ++n) {
                xhv[n] = *(const float4*)&xh[(ng * 4 + n) * H + kbase];
                xmv[n] = *(const float4*)&xm[(ng * 4 + n) * H + kbase];
            }
            float4 wgv0 = *(const float4*)&wgs[(kk + 0) * H + fg * 4];
            float4 wgv1 = *(const float4*)&wgs[(kk + 1) * H + fg * 4];
            float4 wgv2 = *(const float4*)&wgs[(kk + 2) * H + fg * 4];
            float4 wgv3 = *(const float4*)&wgs[(kk + 3) * H + fg * 4];
            float4 wmv0 = *(const float4*)&wms[(kk + 0) * H + fg * 4];
            float4 wmv1 = *(const float4*)&wms[(kk + 1) * H + fg * 4];
            float4 wmv2 = *(const float4*)&wms[(kk + 2) * H + fg * 4];
            float4 wmv3 = *(const float4*)&wms[(kk + 3) * H + fg * 4];
            #pragma unroll
            for (int n = 0; n < 4; ++n) {
                fma4(accg[n], xhv[n].x, wgv0);
                fma4(accg[n], xhv[n].y, wgv1);
                fma4(accg[n], xhv[n].z, wgv2);
                fma4(accg[n], xhv[n].w, wgv3);
                fma4(accm[n], xmv[n].x, wmv0);
                fma4(accm[n], xmv[n].y, wmv1);
                fma4(accm[n], xmv[n].z, wmv2);
                fma4(accm[n], xmv[n].w, wmv3);
            }
        }
    }

    // epilogue: bias, sigmoid gate, residual, LayerNorm
    float4 gb = *(const float4*)&gate_b[fg * 4];
    float4 mb = *(const float4*)&msg_b[fg * 4];
    float4 gmv = *(const float4*)&gamma[fg * 4];
    float4 btv = *(const float4*)&beta[fg * 4];
    #pragma unroll
    for (int n = 0; n < 4; ++n) {
        int nl = ng * 4 + n;
        int gn = tileBase + nl;
        float4 hv = *(const float4*)&xh[nl * H + fg * 4];
        float4 g, m, xr;
        g.x = 1.f / (1.f + expf(-(accg[n].x + gb.x)));
        g.y = 1.f / (1.f + expf(-(accg[n].y + gb.y)));
        g.z = 1.f / (1.f + expf(-(accg[n].z + gb.z)));
        g.w = 1.f / (1.f + expf(-(accg[n].w + gb.w)));
        m.x = accm[n].x + mb.x;
        m.y = accm[n].y + mb.y;
        m.z = accm[n].z + mb.z;
        m.w = accm[n].w + mb.w;
        xr.x = fmaf(g.x, m.x, hv.x);
        xr.y = fmaf(g.y, m.y, hv.y);
        xr.z = fmaf(g.z, m.z, hv.z);
        xr.w = fmaf(g.w, m.w, hv.w);
        float s = xr.x + xr.y + xr.z + xr.w;
        float ss = xr.x * xr.x + xr.y * xr.y + xr.z * xr.z + xr.w * xr.w;
        #pragma unroll
        for (int msk = 1; msk < 32; msk <<= 1) {
            s += __shfl_xor(s, msk);
            ss += __shfl_xor(ss, msk);
        }
        float mu = s * (1.f / 128.f);
        float var = ss * (1.f / 128.f) - mu * mu;
        float rstd = rsqrtf(var + LN_EPS);
        float4 o;
        o.x = (xr.x - mu) * rstd * gmv.x + btv.x;
        o.y = (xr.y - mu) * rstd * gmv.y + btv.y;
        o.z = (xr.z - mu) * rstd * gmv.z + btv.z;
        o.w = (xr.w - mu) * rstd * gmv.w + btv.w;
        if (gn < N) *(float4*)&out[(size_t)gn * H + fg * 4] = o;
    }
}

extern "C" void kernel_launch(void* const* d_in, const int* in_sizes, int n_in,
                              void* d_out, int out_size, void* d_ws, size_t ws_size,
                              hipStream_t stream) {
    const float* hidden = (const float*)d_in[0];
    const int*   ei     = (const int*)d_in[1];     // (2,E) flat: row then col
    const float* msg_W  = (const float*)d_in[2];
    const float* msg_b  = (const float*)d_in[3];
    const float* msg_A  = (const float*)d_in[4];
    const float* msg_B  = (const float*)d_in[5];
    const float* gate_W = (const float*)d_in[6];
    const float* gate_b = (const float*)d_in[7];
    const float* gate_A = (const float*)d_in[8];
    const float* gate_B = (const float*)d_in[9];
    const float* gamma  = (const float*)d_in[10];
    const float* beta   = (const float*)d_in[11];
    float* out = (float*)d_out;

    int N = in_sizes[0] / H;
    int E = in_sizes[1] / 2;

    // workspace layout (floats)
    float* ws = (float*)d_ws;
    float* Wm   = ws;                    // H*H
    float* Wg   = Wm + H * H;            // H*H
    float* dinv = Wg + H * H;            // N
    float* rdeg = dinv + N;              // N
    int*   deg  = (int*)(rdeg + N);      // N

    hipMemsetAsync(deg, 0, (size_t)N * sizeof(int), stream);

    k_deg<<<(E + 255) / 256, 256, 0, stream>>>(ei + E, E, deg);
    k_dinv<<<(N + 255) / 256, 256, 0, stream>>>(deg, N, dinv, rdeg);
    k_weff<<<(H * H + 255) / 256, 256, 0, stream>>>(msg_W, msg_A, msg_B, Wm);
    k_weff<<<(H * H + 255) / 256, 256, 0, stream>>>(gate_W, gate_A, gate_B, Wg);
    // summed lives in d_out
    k_selfinit<<<(N * (H / 4) + 255) / 256, 256, 0, stream>>>(
        (const float4*)hidden, dinv, N, (float4*)out);
    k_scatter<<<((size_t)E * 32 + 255) / 256, 256, 0, stream>>>(
        ei, E, dinv, (const float4*)hidden, out);
    k_fused<<<(N + TILE - 1) / TILE, 256, 0, stream>>>(
        hidden, out, rdeg, Wm, Wg, msg_b, gate_b, gamma, beta, out, N);
}

// Round 3
// 414.222 us; speedup vs baseline: 3.1699x; 3.1699x over previous
//
#include <hip/hip_runtime.h>
#include <math.h>

#define H 128
#define RANK 16
#define SCALING 2.0f
#define LN_EPS 1e-5f
#define TILE 32
#define CHUNK 2048

// ---------------- degree count ----------------
__global__ void k_deg(const int* __restrict__ col, int E, int* __restrict__ deg) {
    int e = blockIdx.x * blockDim.x + threadIdx.x;
    if (e < E) atomicAdd(&deg[col[e]], 1);
}

// ---------------- dinv / rdeg ----------------
__global__ void k_dinv(const int* __restrict__ deg, int N,
                       float* __restrict__ dinv, float* __restrict__ rdeg) {
    int i = blockIdx.x * blockDim.x + threadIdx.x;
    if (i < N) {
        float d = (float)(deg[i] + 1);   // +1 self loop
        dinv[i] = rsqrtf(d);
        rdeg[i] = 1.0f / d;
    }
}

// ---------------- scan pass A: per-chunk sums ----------------
__global__ void k_chunksum(const int* __restrict__ deg, int N, int* __restrict__ chunkSum) {
    __shared__ int red[256];
    int c = blockIdx.x;
    int base = c * CHUNK;
    int s = 0;
    for (int i = threadIdx.x; i < CHUNK; i += 256) {
        int g = base + i;
        if (g < N) s += deg[g];
    }
    red[threadIdx.x] = s;
    __syncthreads();
    for (int off = 128; off > 0; off >>= 1) {
        if (threadIdx.x < off) red[threadIdx.x] += red[threadIdx.x + off];
        __syncthreads();
    }
    if (threadIdx.x == 0) chunkSum[c] = red[0];
}

// ---------------- scan pass B: sequential scan of chunk sums (C ~ 49) ----------------
__global__ void k_chunkscan(const int* __restrict__ chunkSum, int C,
                            int* __restrict__ chunkBase, int* __restrict__ offsets, int N) {
    if (threadIdx.x == 0 && blockIdx.x == 0) {
        int acc = 0;
        for (int c = 0; c < C; ++c) { chunkBase[c] = acc; acc += chunkSum[c]; }
        offsets[N] = acc;   // == E
    }
}

// ---------------- scan pass C: local exclusive scan + write offsets & cursor ----------------
__global__ void k_localscan(const int* __restrict__ deg, int N, const int* __restrict__ chunkBase,
                            int* __restrict__ offsets, int* __restrict__ cursor) {
    int c = blockIdx.x, t = threadIdx.x;
    int base = c * CHUNK;
    int idx0 = base + t * 8;
    int v[8]; int tsum = 0;
    #pragma unroll
    for (int j = 0; j < 8; ++j) {
        int g = idx0 + j;
        v[j] = (g < N) ? deg[g] : 0;
        tsum += v[j];
    }
    int lane = t & 63, wv = t >> 6;
    int inc = tsum;
    #pragma unroll
    for (int off = 1; off < 64; off <<= 1) {
        int u = __shfl_up(inc, off);
        if (lane >= off) inc += u;
    }
    __shared__ int wsum[4];
    if (lane == 63) wsum[wv] = inc;
    __syncthreads();
    int wbase = 0;
    for (int w = 0; w < wv; ++w) wbase += wsum[w];
    int excl = wbase + inc - tsum + chunkBase[c];
    #pragma unroll
    for (int j = 0; j < 8; ++j) {
        int g = idx0 + j;
        if (g < N) { offsets[g] = excl; cursor[g] = excl; excl += v[j]; }
    }
}

// ---------------- CSR fill ----------------
__global__ void k_fill(const int* __restrict__ ei, int E,
                       int* __restrict__ cursor, int* __restrict__ adj) {
    int e = blockIdx.x * blockDim.x + threadIdx.x;
    if (e < E) {
        int r = ei[e];        // source
        int c = ei[E + e];    // target
        int pos = atomicAdd(&cursor[c], 1);
        adj[pos] = r;
    }
}

// ---------------- gather-reduce: one wave per node ----------------
__global__ __launch_bounds__(256) void k_gather(
    const float2* __restrict__ x2, const int* __restrict__ offsets,
    const int* __restrict__ adj, const float* __restrict__ dinv,
    const float* __restrict__ rdeg, int N, float2* __restrict__ out2) {
    int wave = (blockIdx.x * 256 + threadIdx.x) >> 6;
    int lane = threadIdx.x & 63;
    if (wave >= N) return;
    int i = wave;
    float di = dinv[i];
    float2 acc = x2[(size_t)i * 64 + lane];      // self loop: dinv_i * x_i (outer dinv_i applied below)
    acc.x *= di; acc.y *= di;
    int s0 = offsets[i], s1 = offsets[i + 1];
    for (int e = s0; e < s1; ++e) {
        int s = adj[e];
        float w = dinv[s];
        float2 xv = x2[(size_t)s * 64 + lane];
        acc.x = fmaf(w, xv.x, acc.x);
        acc.y = fmaf(w, xv.y, acc.y);
    }
    float sc = di * rdeg[i];                     // dinv_i (norm) * 1/deg (mean)
    acc.x *= sc; acc.y *= sc;
    out2[(size_t)i * 64 + lane] = acc;
}

// ---------------- LoRA fold: Weff[k][h] = W[h][k] + S * sum_r A[r][k]*B[h][r] ----------------
__global__ void k_weff(const float* __restrict__ W, const float* __restrict__ A,
                       const float* __restrict__ B, float* __restrict__ Weff) {
    int idx = blockIdx.x * blockDim.x + threadIdx.x;  // H*H
    if (idx < H * H) {
        int h = idx & (H - 1);
        int k = idx >> 7;
        float s = 0.f;
        #pragma unroll
        for (int r = 0; r < RANK; ++r) s = fmaf(A[r * H + k], B[h * RANK + r], s);
        Weff[k * H + h] = W[h * H + k] + SCALING * s;
    }
}

// ---------------- fused: both GEMMs + sigmoid gate + residual + LayerNorm ----------------
__device__ __forceinline__ void fma4(float4& acc, float s, const float4& wv) {
    acc.x = fmaf(s, wv.x, acc.x);
    acc.y = fmaf(s, wv.y, acc.y);
    acc.z = fmaf(s, wv.z, acc.z);
    acc.w = fmaf(s, wv.w, acc.w);
}

__global__ __launch_bounds__(256, 2) void k_fused(
    const float* __restrict__ hidden, const float* summed,
    const float* __restrict__ Wm, const float* __restrict__ Wg,
    const float* __restrict__ msg_b, const float* __restrict__ gate_b,
    const float* __restrict__ gamma, const float* __restrict__ beta,
    float* out, int N) {
    __shared__ float xh[TILE * H];
    __shared__ float xm[TILE * H];
    __shared__ float wgs[32 * H];
    __shared__ float wms[32 * H];

    int t = threadIdx.x;
    int tileBase = blockIdx.x * TILE;

    const float4* h4 = (const float4*)(hidden + (size_t)tileBase * H);
    const float4* s4 = (const float4*)(summed + (size_t)tileBase * H);
    float4* xh4 = (float4*)xh;
    float4* xm4 = (float4*)xm;
    #pragma unroll
    for (int i = 0; i < 4; ++i) {
        int idx = t + i * 256;       // 1024 float4s = 32 rows
        int n = idx >> 5;
        int gn = tileBase + n;
        float4 hv = make_float4(0.f, 0.f, 0.f, 0.f);
        float4 sv = make_float4(0.f, 0.f, 0.f, 0.f);
        if (gn < N) {
            hv = h4[idx];
            sv = s4[idx];
        }
        xh4[idx] = hv;
        xm4[idx] = sv;
    }

    int fg = t & 31;   // feature group
    int ng = t >> 5;   // node group
    float4 accg[4], accm[4];
    #pragma unroll
    for (int n = 0; n < 4; ++n) {
        accg[n] = make_float4(0.f, 0.f, 0.f, 0.f);
        accm[n] = make_float4(0.f, 0.f, 0.f, 0.f);
    }

    for (int c = 0; c < 4; ++c) {
        __syncthreads();
        const float4* wg4 = (const float4*)(Wg + c * 32 * H);
        const float4* wm4 = (const float4*)(Wm + c * 32 * H);
        #pragma unroll
        for (int i = 0; i < 4; ++i) {
            ((float4*)wgs)[t + i * 256] = wg4[t + i * 256];
            ((float4*)wms)[t + i * 256] = wm4[t + i * 256];
        }
        __syncthreads();
        #pragma unroll
        for (int kk = 0; kk < 32; kk += 4) {
            int kbase = c * 32 + kk;
            float4 xhv[4], xmv[4];
            #pragma unroll
            for (int n = 0; n < 4; ++n) {
                xhv[n] = *(const float4*)&xh[(ng * 4 + n) * H + kbase];
                xmv[n] = *(const float4*)&xm[(ng * 4 + n) * H + kbase];
            }
            float4 wgv0 = *(const float4*)&wgs[(kk + 0) * H + fg * 4];
            float4 wgv1 = *(const float4*)&wgs[(kk + 1) * H + fg * 4];
            float4 wgv2 = *(const float4*)&wgs[(kk + 2) * H + fg * 4];
            float4 wgv3 = *(const float4*)&wgs[(kk + 3) * H + fg * 4];
            float4 wmv0 = *(const float4*)&wms[(kk + 0) * H + fg * 4];
            float4 wmv1 = *(const float4*)&wms[(kk + 1) * H + fg * 4];
            float4 wmv2 = *(const float4*)&wms[(kk + 2) * H + fg * 4];
            float4 wmv3 = *(const float4*)&wms[(kk + 3) * H + fg * 4];
            #pragma unroll
            for (int n = 0; n < 4; ++n) {
                fma4(accg[n], xhv[n].x, wgv0);
                fma4(accg[n], xhv[n].y, wgv1);
                fma4(accg[n], xhv[n].z, wgv2);
                fma4(accg[n], xhv[n].w, wgv3);
                fma4(accm[n], xmv[n].x, wmv0);
                fma4(accm[n], xmv[n].y, wmv1);
                fma4(accm[n], xmv[n].z, wmv2);
                fma4(accm[n], xmv[n].w, wmv3);
            }
        }
    }

    float4 gb = *(const float4*)&gate_b[fg * 4];
    float4 mb = *(const float4*)&msg_b[fg * 4];
    float4 gmv = *(const float4*)&gamma[fg * 4];
    float4 btv = *(const float4*)&beta[fg * 4];
    #pragma unroll
    for (int n = 0; n < 4; ++n) {
        int nl = ng * 4 + n;
        int gn = tileBase + nl;
        float4 hv = *(const float4*)&xh[nl * H + fg * 4];
        float4 g, m, xr;
        g.x = 1.f / (1.f + expf(-(accg[n].x + gb.x)));
        g.y = 1.f / (1.f + expf(-(accg[n].y + gb.y)));
        g.z = 1.f / (1.f + expf(-(accg[n].z + gb.z)));
        g.w = 1.f / (1.f + expf(-(accg[n].w + gb.w)));
        m.x = accm[n].x + mb.x;
        m.y = accm[n].y + mb.y;
        m.z = accm[n].z + mb.z;
        m.w = accm[n].w + mb.w;
        xr.x = fmaf(g.x, m.x, hv.x);
        xr.y = fmaf(g.y, m.y, hv.y);
        xr.z = fmaf(g.z, m.z, hv.z);
        xr.w = fmaf(g.w, m.w, hv.w);
        float s = xr.x + xr.y + xr.z + xr.w;
        float ss = xr.x * xr.x + xr.y * xr.y + xr.z * xr.z + xr.w * xr.w;
        #pragma unroll
        for (int msk = 1; msk < 32; msk <<= 1) {
            s += __shfl_xor(s, msk);
            ss += __shfl_xor(ss, msk);
        }
        float mu = s * (1.f / 128.f);
        float var = ss * (1.f / 128.f) - mu * mu;
        float rstd = rsqrtf(var + LN_EPS);
        float4 o;
        o.x = (xr.x - mu) * rstd * gmv.x + btv.x;
        o.y = (xr.y - mu) * rstd * gmv.y + btv.y;
        o.z = (xr.z - mu) * rstd * gmv.z + btv.z;
        o.w = (xr.w - mu) * rstd * gmv.w + btv.w;
        if (gn < N) *(float4*)&out[(size_t)gn * H + fg * 4] = o;
    }
}

extern "C" void kernel_launch(void* const* d_in, const int* in_sizes, int n_in,
                              void* d_out, int out_size, void* d_ws, size_t ws_size,
                              hipStream_t stream) {
    const float* hidden = (const float*)d_in[0];
    const int*   ei     = (const int*)d_in[1];     // (2,E) flat: row then col
    const float* msg_W  = (const float*)d_in[2];
    const float* msg_b  = (const float*)d_in[3];
    const float* msg_A  = (const float*)d_in[4];
    const float* msg_B  = (const float*)d_in[5];
    const float* gate_W = (const float*)d_in[6];
    const float* gate_b = (const float*)d_in[7];
    const float* gate_A = (const float*)d_in[8];
    const float* gate_B = (const float*)d_in[9];
    const float* gamma  = (const float*)d_in[10];
    const float* beta   = (const float*)d_in[11];
    float* out = (float*)d_out;

    int N = in_sizes[0] / H;
    int E = in_sizes[1] / 2;
    int C = (N + CHUNK - 1) / CHUNK;

    // workspace layout
    char* p = (char*)d_ws;
    float* Wm   = (float*)p;               p += H * H * sizeof(float);
    float* Wg   = (float*)p;               p += H * H * sizeof(float);
    float* dinv = (float*)p;               p += (size_t)N * sizeof(float);
    float* rdeg = (float*)p;               p += (size_t)N * sizeof(float);
    int*   deg  = (int*)p;                 p += (size_t)N * sizeof(int);
    int*   offsets = (int*)p;              p += (size_t)(N + 1) * sizeof(int);
    int*   cursor  = (int*)p;              p += (size_t)N * sizeof(int);
    int*   chunkSum  = (int*)p;            p += (size_t)C * sizeof(int);
    int*   chunkBase = (int*)p;            p += (size_t)C * sizeof(int);
    int*   adj  = (int*)p;                 p += (size_t)E * sizeof(int);

    hipMemsetAsync(deg, 0, (size_t)N * sizeof(int), stream);

    k_deg<<<(E + 255) / 256, 256, 0, stream>>>(ei + E, E, deg);
    k_dinv<<<(N + 255) / 256, 256, 0, stream>>>(deg, N, dinv, rdeg);
    k_chunksum<<<C, 256, 0, stream>>>(deg, N, chunkSum);
    k_chunkscan<<<1, 64, 0, stream>>>(chunkSum, C, chunkBase, offsets, N);
    k_localscan<<<C, 256, 0, stream>>>(deg, N, chunkBase, offsets, cursor);
    k_fill<<<(E + 255) / 256, 256, 0, stream>>>(ei, E, cursor, adj);
    k_weff<<<(H * H + 255) / 256, 256, 0, stream>>>(msg_W, msg_A, msg_B, Wm);
    k_weff<<<(H * H + 255) / 256, 256, 0, stream>>>(gate_W, gate_A, gate_B, Wg);
    // mean-divided messages land in d_out
    k_gather<<<((size_t)N * 64 + 255) / 256, 256, 0, stream>>>(
        (const float2*)hidden, offsets, adj, dinv, rdeg, N, (float2*)out);
    k_fused<<<(N + TILE - 1) / TILE, 256, 0, stream>>>(
        hidden, out, Wm, Wg, msg_b, gate_b, gamma, beta, out, N);
}

// Round 4
// 309.072 us; speedup vs baseline: 4.2483x; 1.3402x over previous
//
#include <hip/hip_runtime.h>
#include <math.h>

#define H 128
#define RANK 16
#define SCALING 2.0f
#define LN_EPS 1e-5f
#define CHUNK 2048

typedef short bf16x8 __attribute__((ext_vector_type(8)));
typedef float f32x4 __attribute__((ext_vector_type(4)));

__device__ __forceinline__ unsigned short f2bf(float f) {
    unsigned int u = __float_as_uint(f);
    u += 0x7fffu + ((u >> 16) & 1u);
    return (unsigned short)(u >> 16);
}

__device__ __forceinline__ bf16x8 pack8(float4 a, float4 b) {
    bf16x8 r;
    r[0] = (short)f2bf(a.x); r[1] = (short)f2bf(a.y);
    r[2] = (short)f2bf(a.z); r[3] = (short)f2bf(a.w);
    r[4] = (short)f2bf(b.x); r[5] = (short)f2bf(b.y);
    r[6] = (short)f2bf(b.z); r[7] = (short)f2bf(b.w);
    return r;
}

// ---------------- degree count ----------------
__global__ void k_deg(const int* __restrict__ col, int E, int* __restrict__ deg) {
    int e = blockIdx.x * blockDim.x + threadIdx.x;
    if (e < E) atomicAdd(&deg[col[e]], 1);
}

// ---------------- dinv / rdeg ----------------
__global__ void k_dinv(const int* __restrict__ deg, int N,
                       float* __restrict__ dinv, float* __restrict__ rdeg) {
    int i = blockIdx.x * blockDim.x + threadIdx.x;
    if (i < N) {
        float d = (float)(deg[i] + 1);   // +1 self loop
        dinv[i] = rsqrtf(d);
        rdeg[i] = 1.0f / d;
    }
}

// ---------------- scan pass A: per-chunk sums ----------------
__global__ void k_chunksum(const int* __restrict__ deg, int N, int* __restrict__ chunkSum) {
    __shared__ int red[256];
    int c = blockIdx.x;
    int base = c * CHUNK;
    int s = 0;
    for (int i = threadIdx.x; i < CHUNK; i += 256) {
        int g = base + i;
        if (g < N) s += deg[g];
    }
    red[threadIdx.x] = s;
    __syncthreads();
    for (int off = 128; off > 0; off >>= 1) {
        if (threadIdx.x < off) red[threadIdx.x] += red[threadIdx.x + off];
        __syncthreads();
    }
    if (threadIdx.x == 0) chunkSum[c] = red[0];
}

// ---------------- scan pass B: sequential scan of chunk sums ----------------
__global__ void k_chunkscan(const int* __restrict__ chunkSum, int C,
                            int* __restrict__ chunkBase, int* __restrict__ offsets, int N) {
    if (threadIdx.x == 0 && blockIdx.x == 0) {
        int acc = 0;
        for (int c = 0; c < C; ++c) { chunkBase[c] = acc; acc += chunkSum[c]; }
        offsets[N] = acc;   // == E
    }
}

// ---------------- scan pass C: local exclusive scan ----------------
__global__ void k_localscan(const int* __restrict__ deg, int N, const int* __restrict__ chunkBase,
                            int* __restrict__ offsets, int* __restrict__ cursor) {
    int c = blockIdx.x, t = threadIdx.x;
    int base = c * CHUNK;
    int idx0 = base + t * 8;
    int v[8]; int tsum = 0;
    #pragma unroll
    for (int j = 0; j < 8; ++j) {
        int g = idx0 + j;
        v[j] = (g < N) ? deg[g] : 0;
        tsum += v[j];
    }
    int lane = t & 63, wv = t >> 6;
    int inc = tsum;
    #pragma unroll
    for (int off = 1; off < 64; off <<= 1) {
        int u = __shfl_up(inc, off);
        if (lane >= off) inc += u;
    }
    __shared__ int wsum[4];
    if (lane == 63) wsum[wv] = inc;
    __syncthreads();
    int wbase = 0;
    for (int w = 0; w < wv; ++w) wbase += wsum[w];
    int excl = wbase + inc - tsum + chunkBase[c];
    #pragma unroll
    for (int j = 0; j < 8; ++j) {
        int g = idx0 + j;
        if (g < N) { offsets[g] = excl; cursor[g] = excl; excl += v[j]; }
    }
}

// ---------------- CSR fill ----------------
__global__ void k_fill(const int* __restrict__ ei, int E,
                       int* __restrict__ cursor, int* __restrict__ adj) {
    int e = blockIdx.x * blockDim.x + threadIdx.x;
    if (e < E) {
        int r = ei[e];        // source
        int c = ei[E + e];    // target
        int pos = atomicAdd(&cursor[c], 1);
        adj[pos] = r;
    }
}

// ---------------- gather-reduce: one wave per node ----------------
__global__ __launch_bounds__(256) void k_gather(
    const float2* __restrict__ x2, const int* __restrict__ offsets,
    const int* __restrict__ adj, const float* __restrict__ dinv,
    const float* __restrict__ rdeg, int N, float2* __restrict__ out2) {
    int wave = (blockIdx.x * 256 + threadIdx.x) >> 6;
    int lane = threadIdx.x & 63;
    if (wave >= N) return;
    int i = wave;
    float di = dinv[i];
    float2 acc = x2[(size_t)i * 64 + lane];      // self loop
    acc.x *= di; acc.y *= di;
    int s0 = offsets[i], s1 = offsets[i + 1];
    for (int e = s0; e < s1; ++e) {
        int s = adj[e];
        float w = dinv[s];
        float2 xv = x2[(size_t)s * 64 + lane];
        acc.x = fmaf(w, xv.x, acc.x);
        acc.y = fmaf(w, xv.y, acc.y);
    }
    float sc = di * rdeg[i];                     // dinv_i (norm) * 1/deg (mean)
    acc.x *= sc; acc.y *= sc;
    out2[(size_t)i * 64 + lane] = acc;
}

// ---------------- LoRA fold -> bf16, pre-swizzled into B-fragment order ----------------
// Weff[k][n] = W[n][k] + S * sum_r A[r][k]*B[n][r]
// B-fragment layout for mfma_f32_16x16x32_bf16: lane = (k_sub>>3)*16 + (n&15),
// j = k&7; frag (ktile, ntile) stored contiguously.
__global__ void k_weff_bf(const float* __restrict__ W, const float* __restrict__ A,
                          const float* __restrict__ B, unsigned short* __restrict__ Wz) {
    int idx = blockIdx.x * blockDim.x + threadIdx.x;  // H*H
    if (idx < H * H) {
        int h = idx & (H - 1);   // output feature n
        int k = idx >> 7;
        float s = 0.f;
        #pragma unroll
        for (int r = 0; r < RANK; ++r) s = fmaf(A[r * H + k], B[h * RANK + r], s);
        float v = W[h * H + k] + SCALING * s;
        int kt = k >> 5, kk = k & 31, qd = kk >> 3, j = kk & 7;
        int nt = h >> 4, nl = h & 15;
        int lane = qd * 16 + nl;
        Wz[(((kt * 8 + nt) * 64 + lane) * 8) + j] = f2bf(v);
    }
}

// ---------------- fused: both GEMMs (bf16 MFMA) + gate + residual + LayerNorm ----------------
// One wave = 16 nodes x 128 features x 2 GEMMs. No LDS.
__global__ __launch_bounds__(256) void k_fused(
    const float* __restrict__ hidden, const float* summed,
    const unsigned short* __restrict__ Wmz, const unsigned short* __restrict__ Wgz,
    const float* __restrict__ msg_b, const float* __restrict__ gate_b,
    const float* __restrict__ gamma, const float* __restrict__ beta,
    float* out, int N) {
    int t = threadIdx.x;
    int wid = t >> 6, lane = t & 63;
    int m0 = (blockIdx.x * 4 + wid) * 16;
    if (m0 >= N) return;

    int quad = lane >> 4;   // 0..3
    int nl = lane & 15;

    // A-operand rows: this lane supplies node m0+nl, k = kt*32 + quad*8 + j
    const float4* ha4 = (const float4*)(hidden + (size_t)(m0 + nl) * H);
    const float4* ma4 = (const float4*)(summed + (size_t)(m0 + nl) * H);

    f32x4 accg[8], accm[8];
    #pragma unroll
    for (int nt = 0; nt < 8; ++nt) {
        accg[nt] = (f32x4)(0.f);
        accm[nt] = (f32x4)(0.f);
    }

    #pragma unroll
    for (int kt = 0; kt < 4; ++kt) {
        int o = kt * 8 + quad * 2;
        bf16x8 ah = pack8(ha4[o], ha4[o + 1]);
        bf16x8 am = pack8(ma4[o], ma4[o + 1]);
        const bf16x8* bg8 = (const bf16x8*)(Wgz + (size_t)kt * 4096);
        const bf16x8* bm8 = (const bf16x8*)(Wmz + (size_t)kt * 4096);
        #pragma unroll
        for (int nt = 0; nt < 8; ++nt) {
            bf16x8 bg = bg8[nt * 64 + lane];
            bf16x8 bm = bm8[nt * 64 + lane];
            accg[nt] = __builtin_amdgcn_mfma_f32_16x16x32_bf16(ah, bg, accg[nt], 0, 0, 0);
            accm[nt] = __builtin_amdgcn_mfma_f32_16x16x32_bf16(am, bm, accm[nt], 0, 0, 0);
        }
    }

    // per-lane column constants
    float gb[8], mb[8], gm[8], bt[8];
    #pragma unroll
    for (int nt = 0; nt < 8; ++nt) {
        int col = nt * 16 + nl;
        gb[nt] = gate_b[col]; mb[nt] = msg_b[col];
        gm[nt] = gamma[col];  bt[nt] = beta[col];
    }

    // C/D layout: node = m0 + quad*4 + reg, col = nt*16 + nl
    #pragma unroll
    for (int r = 0; r < 4; ++r) {
        int node = m0 + quad * 4 + r;
        const float* hrow = hidden + (size_t)node * H;
        float xr[8]; float s = 0.f, ss = 0.f;
        #pragma unroll
        for (int nt = 0; nt < 8; ++nt) {
            int col = nt * 16 + nl;
            float g = 1.f / (1.f + __expf(-(accg[nt][r] + gb[nt])));
            float m = accm[nt][r] + mb[nt];
            float v = fmaf(g, m, hrow[col]);
            xr[nt] = v; s += v; ss = fmaf(v, v, ss);
        }
        #pragma unroll
        for (int msk = 1; msk < 16; msk <<= 1) {
            s += __shfl_xor(s, msk);
            ss += __shfl_xor(ss, msk);
        }
        float mu = s * (1.f / 128.f);
        float var = ss * (1.f / 128.f) - mu * mu;
        float rstd = rsqrtf(var + LN_EPS);
        float* orow = out + (size_t)node * H;
        #pragma unroll
        for (int nt = 0; nt < 8; ++nt)
            orow[nt * 16 + nl] = (xr[nt] - mu) * rstd * gm[nt] + bt[nt];
    }
}

extern "C" void kernel_launch(void* const* d_in, const int* in_sizes, int n_in,
                              void* d_out, int out_size, void* d_ws, size_t ws_size,
                              hipStream_t stream) {
    const float* hidden = (const float*)d_in[0];
    const int*   ei     = (const int*)d_in[1];     // (2,E) flat: row then col
    const float* msg_W  = (const float*)d_in[2];
    const float* msg_b  = (const float*)d_in[3];
    const float* msg_A  = (const float*)d_in[4];
    const float* msg_B  = (const float*)d_in[5];
    const float* gate_W = (const float*)d_in[6];
    const float* gate_b = (const float*)d_in[7];
    const float* gate_A = (const float*)d_in[8];
    const float* gate_B = (const float*)d_in[9];
    const float* gamma  = (const float*)d_in[10];
    const float* beta   = (const float*)d_in[11];
    float* out = (float*)d_out;

    int N = in_sizes[0] / H;
    int E = in_sizes[1] / 2;
    int C = (N + CHUNK - 1) / CHUNK;

    // workspace layout
    char* p = (char*)d_ws;
    unsigned short* Wmz = (unsigned short*)p;  p += (size_t)H * H * sizeof(unsigned short);
    unsigned short* Wgz = (unsigned short*)p;  p += (size_t)H * H * sizeof(unsigned short);
    float* dinv = (float*)p;               p += (size_t)N * sizeof(float);
    float* rdeg = (float*)p;               p += (size_t)N * sizeof(float);
    int*   deg  = (int*)p;                 p += (size_t)N * sizeof(int);
    int*   offsets = (int*)p;              p += (size_t)(N + 1) * sizeof(int);
    int*   cursor  = (int*)p;              p += (size_t)N * sizeof(int);
    int*   chunkSum  = (int*)p;            p += (size_t)C * sizeof(int);
    int*   chunkBase = (int*)p;            p += (size_t)C * sizeof(int);
    int*   adj  = (int*)p;                 p += (size_t)E * sizeof(int);

    hipMemsetAsync(deg, 0, (size_t)N * sizeof(int), stream);

    k_deg<<<(E + 255) / 256, 256, 0, stream>>>(ei + E, E, deg);
    k_dinv<<<(N + 255) / 256, 256, 0, stream>>>(deg, N, dinv, rdeg);
    k_chunksum<<<C, 256, 0, stream>>>(deg, N, chunkSum);
    k_chunkscan<<<1, 64, 0, stream>>>(chunkSum, C, chunkBase, offsets, N);
    k_localscan<<<C, 256, 0, stream>>>(deg, N, chunkBase, offsets, cursor);
    k_fill<<<(E + 255) / 256, 256, 0, stream>>>(ei, E, cursor, adj);
    k_weff_bf<<<(H * H + 255) / 256, 256, 0, stream>>>(msg_W, msg_A, msg_B, Wmz);
    k_weff_bf<<<(H * H + 255) / 256, 256, 0, stream>>>(gate_W, gate_A, gate_B, Wgz);
    // mean-divided messages land in d_out
    k_gather<<<((size_t)N * 64 + 255) / 256, 256, 0, stream>>>(
        (const float2*)hidden, offsets, adj, dinv, rdeg, N, (float2*)out);
    int waves = (N + 15) / 16;
    k_fused<<<(waves + 3) / 4, 256, 0, stream>>>(
        hidden, out, Wmz, Wgz, msg_b, gate_b, gamma, beta, out, N);
}

// Round 5
// 285.127 us; speedup vs baseline: 4.6051x; 1.0840x over previous
//
#include <hip/hip_runtime.h>
#include <math.h>

#define H 128
#define RANK 16
#define SCALING 2.0f
#define LN_EPS 1e-5f
#define CHUNK 2048

typedef short bf16x8 __attribute__((ext_vector_type(8)));
typedef float f32x4 __attribute__((ext_vector_type(4)));

__device__ __forceinline__ unsigned short f2bf(float f) {
    unsigned int u = __float_as_uint(f);
    u += 0x7fffu + ((u >> 16) & 1u);
    return (unsigned short)(u >> 16);
}

__device__ __forceinline__ bf16x8 pack8(float4 a, float4 b) {
    bf16x8 r;
    r[0] = (short)f2bf(a.x); r[1] = (short)f2bf(a.y);
    r[2] = (short)f2bf(a.z); r[3] = (short)f2bf(a.w);
    r[4] = (short)f2bf(b.x); r[5] = (short)f2bf(b.y);
    r[6] = (short)f2bf(b.z); r[7] = (short)f2bf(b.w);
    return r;
}

// ---------------- degree count ----------------
__global__ void k_deg(const int* __restrict__ col, int E, int* __restrict__ deg) {
    int e = blockIdx.x * blockDim.x + threadIdx.x;
    if (e < E) atomicAdd(&deg[col[e]], 1);
}

// ---------------- dinv / rdeg ----------------
__global__ void k_dinv(const int* __restrict__ deg, int N,
                       float* __restrict__ dinv, float* __restrict__ rdeg) {
    int i = blockIdx.x * blockDim.x + threadIdx.x;
    if (i < N) {
        float d = (float)(deg[i] + 1);   // +1 self loop
        dinv[i] = rsqrtf(d);
        rdeg[i] = 1.0f / d;
    }
}

// ---------------- scan pass A: per-chunk sums ----------------
__global__ void k_chunksum(const int* __restrict__ deg, int N, int* __restrict__ chunkSum) {
    __shared__ int red[256];
    int c = blockIdx.x;
    int base = c * CHUNK;
    int s = 0;
    for (int i = threadIdx.x; i < CHUNK; i += 256) {
        int g = base + i;
        if (g < N) s += deg[g];
    }
    red[threadIdx.x] = s;
    __syncthreads();
    for (int off = 128; off > 0; off >>= 1) {
        if (threadIdx.x < off) red[threadIdx.x] += red[threadIdx.x + off];
        __syncthreads();
    }
    if (threadIdx.x == 0) chunkSum[c] = red[0];
}

// ---------------- scan pass B: sequential scan of chunk sums ----------------
__global__ void k_chunkscan(const int* __restrict__ chunkSum, int C,
                            int* __restrict__ chunkBase, int* __restrict__ offsets, int N) {
    if (threadIdx.x == 0 && blockIdx.x == 0) {
        int acc = 0;
        for (int c = 0; c < C; ++c) { chunkBase[c] = acc; acc += chunkSum[c]; }
        offsets[N] = acc;   // == E
    }
}

// ---------------- scan pass C: local exclusive scan ----------------
__global__ void k_localscan(const int* __restrict__ deg, int N, const int* __restrict__ chunkBase,
                            int* __restrict__ offsets, int* __restrict__ cursor) {
    int c = blockIdx.x, t = threadIdx.x;
    int base = c * CHUNK;
    int idx0 = base + t * 8;
    int v[8]; int tsum = 0;
    #pragma unroll
    for (int j = 0; j < 8; ++j) {
        int g = idx0 + j;
        v[j] = (g < N) ? deg[g] : 0;
        tsum += v[j];
    }
    int lane = t & 63, wv = t >> 6;
    int inc = tsum;
    #pragma unroll
    for (int off = 1; off < 64; off <<= 1) {
        int u = __shfl_up(inc, off);
        if (lane >= off) inc += u;
    }
    __shared__ int wsum[4];
    if (lane == 63) wsum[wv] = inc;
    __syncthreads();
    int wbase = 0;
    for (int w = 0; w < wv; ++w) wbase += wsum[w];
    int excl = wbase + inc - tsum + chunkBase[c];
    #pragma unroll
    for (int j = 0; j < 8; ++j) {
        int g = idx0 + j;
        if (g < N) { offsets[g] = excl; cursor[g] = excl; excl += v[j]; }
    }
}

// ---------------- CSR fill ----------------
__global__ void k_fill(const int* __restrict__ ei, int E,
                       int* __restrict__ cursor, int* __restrict__ adj) {
    int e = blockIdx.x * blockDim.x + threadIdx.x;
    if (e < E) {
        int r = ei[e];        // source
        int c = ei[E + e];    // target
        int pos = atomicAdd(&cursor[c], 1);
        adj[pos] = r;
    }
}

// ---------------- gather-reduce: one wave per node, 4x edge-batched for MLP ----------------
__global__ __launch_bounds__(256) void k_gather(
    const float2* __restrict__ x2, const int* __restrict__ offsets,
    const int* __restrict__ adj, const float* __restrict__ dinv,
    const float* __restrict__ rdeg, int N, float2* __restrict__ out2) {
    int wave = (blockIdx.x * 256 + threadIdx.x) >> 6;
    int lane = threadIdx.x & 63;
    if (wave >= N) return;
    int i = wave;
    float di = dinv[i];
    float2 a0 = x2[(size_t)i * 64 + lane];      // self loop
    a0.x *= di; a0.y *= di;
    float2 a1 = make_float2(0.f, 0.f);
    float2 a2 = make_float2(0.f, 0.f);
    float2 a3 = make_float2(0.f, 0.f);
    int e = offsets[i], s1 = offsets[i + 1];
    // 4-edge batches: independent loads issue together (4x MLP)
    for (; e + 4 <= s1; e += 4) {
        int i0 = adj[e], i1 = adj[e + 1], i2 = adj[e + 2], i3 = adj[e + 3];
        float w0 = dinv[i0], w1 = dinv[i1], w2 = dinv[i2], w3 = dinv[i3];
        float2 v0 = x2[(size_t)i0 * 64 + lane];
        float2 v1 = x2[(size_t)i1 * 64 + lane];
        float2 v2 = x2[(size_t)i2 * 64 + lane];
        float2 v3 = x2[(size_t)i3 * 64 + lane];
        a0.x = fmaf(w0, v0.x, a0.x); a0.y = fmaf(w0, v0.y, a0.y);
        a1.x = fmaf(w1, v1.x, a1.x); a1.y = fmaf(w1, v1.y, a1.y);
        a2.x = fmaf(w2, v2.x, a2.x); a2.y = fmaf(w2, v2.y, a2.y);
        a3.x = fmaf(w3, v3.x, a3.x); a3.y = fmaf(w3, v3.y, a3.y);
    }
    if (e + 2 <= s1) {
        int i0 = adj[e], i1 = adj[e + 1];
        float w0 = dinv[i0], w1 = dinv[i1];
        float2 v0 = x2[(size_t)i0 * 64 + lane];
        float2 v1 = x2[(size_t)i1 * 64 + lane];
        a0.x = fmaf(w0, v0.x, a0.x); a0.y = fmaf(w0, v0.y, a0.y);
        a1.x = fmaf(w1, v1.x, a1.x); a1.y = fmaf(w1, v1.y, a1.y);
        e += 2;
    }
    if (e < s1) {
        int i0 = adj[e];
        float w0 = dinv[i0];
        float2 v0 = x2[(size_t)i0 * 64 + lane];
        a2.x = fmaf(w0, v0.x, a2.x); a2.y = fmaf(w0, v0.y, a2.y);
    }
    float sc = di * rdeg[i];                     // dinv_i (norm) * 1/deg (mean)
    float2 acc;
    acc.x = ((a0.x + a1.x) + (a2.x + a3.x)) * sc;
    acc.y = ((a0.y + a1.y) + (a2.y + a3.y)) * sc;
    out2[(size_t)i * 64 + lane] = acc;
}

// ---------------- LoRA fold -> bf16, pre-swizzled into B-fragment order ----------------
__global__ void k_weff_bf(const float* __restrict__ W, const float* __restrict__ A,
                          const float* __restrict__ B, unsigned short* __restrict__ Wz) {
    int idx = blockIdx.x * blockDim.x + threadIdx.x;  // H*H
    if (idx < H * H) {
        int h = idx & (H - 1);   // output feature n
        int k = idx >> 7;
        float s = 0.f;
        #pragma unroll
        for (int r = 0; r < RANK; ++r) s = fmaf(A[r * H + k], B[h * RANK + r], s);
        float v = W[h * H + k] + SCALING * s;
        int kt = k >> 5, kk = k & 31, qd = kk >> 3, j = kk & 7;
        int nt = h >> 4, nl = h & 15;
        int lane = qd * 16 + nl;
        Wz[(((kt * 8 + nt) * 64 + lane) * 8) + j] = f2bf(v);
    }
}

// ---------------- fused: both GEMMs (bf16 MFMA) + gate + residual + LayerNorm ----------------
__global__ __launch_bounds__(256) void k_fused(
    const float* __restrict__ hidden, const float* summed,
    const unsigned short* __restrict__ Wmz, const unsigned short* __restrict__ Wgz,
    const float* __restrict__ msg_b, const float* __restrict__ gate_b,
    const float* __restrict__ gamma, const float* __restrict__ beta,
    float* out, int N) {
    int t = threadIdx.x;
    int wid = t >> 6, lane = t & 63;
    int m0 = (blockIdx.x * 4 + wid) * 16;
    if (m0 >= N) return;

    int quad = lane >> 4;   // 0..3
    int nl = lane & 15;

    const float4* ha4 = (const float4*)(hidden + (size_t)(m0 + nl) * H);
    const float4* ma4 = (const float4*)(summed + (size_t)(m0 + nl) * H);

    f32x4 accg[8], accm[8];
    #pragma unroll
    for (int nt = 0; nt < 8; ++nt) {
        accg[nt] = (f32x4)(0.f);
        accm[nt] = (f32x4)(0.f);
    }

    #pragma unroll
    for (int kt = 0; kt < 4; ++kt) {
        int o = kt * 8 + quad * 2;
        bf16x8 ah = pack8(ha4[o], ha4[o + 1]);
        bf16x8 am = pack8(ma4[o], ma4[o + 1]);
        const bf16x8* bg8 = (const bf16x8*)(Wgz + (size_t)kt * 4096);
        const bf16x8* bm8 = (const bf16x8*)(Wmz + (size_t)kt * 4096);
        #pragma unroll
        for (int nt = 0; nt < 8; ++nt) {
            bf16x8 bg = bg8[nt * 64 + lane];
            bf16x8 bm = bm8[nt * 64 + lane];
            accg[nt] = __builtin_amdgcn_mfma_f32_16x16x32_bf16(ah, bg, accg[nt], 0, 0, 0);
            accm[nt] = __builtin_amdgcn_mfma_f32_16x16x32_bf16(am, bm, accm[nt], 0, 0, 0);
        }
    }

    float gb[8], mb[8], gm[8], bt[8];
    #pragma unroll
    for (int nt = 0; nt < 8; ++nt) {
        int col = nt * 16 + nl;
        gb[nt] = gate_b[col]; mb[nt] = msg_b[col];
        gm[nt] = gamma[col];  bt[nt] = beta[col];
    }

    // C/D layout: node = m0 + quad*4 + reg, col = nt*16 + nl
    #pragma unroll
    for (int r = 0; r < 4; ++r) {
        int node = m0 + quad * 4 + r;
        const float* hrow = hidden + (size_t)node * H;
        float xr[8]; float s = 0.f, ss = 0.f;
        #pragma unroll
        for (int nt = 0; nt < 8; ++nt) {
            int col = nt * 16 + nl;
            float g = 1.f / (1.f + __expf(-(accg[nt][r] + gb[nt])));
            float m = accm[nt][r] + mb[nt];
            float v = fmaf(g, m, hrow[col]);
            xr[nt] = v; s += v; ss = fmaf(v, v, ss);
        }
        #pragma unroll
        for (int msk = 1; msk < 16; msk <<= 1) {
            s += __shfl_xor(s, msk);
            ss += __shfl_xor(ss, msk);
        }
        float mu = s * (1.f / 128.f);
        float var = ss * (1.f / 128.f) - mu * mu;
        float rstd = rsqrtf(var + LN_EPS);
        float* orow = out + (size_t)node * H;
        #pragma unroll
        for (int nt = 0; nt < 8; ++nt)
            orow[nt * 16 + nl] = (xr[nt] - mu) * rstd * gm[nt] + bt[nt];
    }
}

extern "C" void kernel_launch(void* const* d_in, const int* in_sizes, int n_in,
                              void* d_out, int out_size, void* d_ws, size_t ws_size,
                              hipStream_t stream) {
    const float* hidden = (const float*)d_in[0];
    const int*   ei     = (const int*)d_in[1];     // (2,E) flat: row then col
    const float* msg_W  = (const float*)d_in[2];
    const float* msg_b  = (const float*)d_in[3];
    const float* msg_A  = (const float*)d_in[4];
    const float* msg_B  = (const float*)d_in[5];
    const float* gate_W = (const float*)d_in[6];
    const float* gate_b = (const float*)d_in[7];
    const float* gate_A = (const float*)d_in[8];
    const float* gate_B = (const float*)d_in[9];
    const float* gamma  = (const float*)d_in[10];
    const float* beta   = (const float*)d_in[11];
    float* out = (float*)d_out;

    int N = in_sizes[0] / H;
    int E = in_sizes[1] / 2;
    int C = (N + CHUNK - 1) / CHUNK;

    // workspace layout
    char* p = (char*)d_ws;
    unsigned short* Wmz = (unsigned short*)p;  p += (size_t)H * H * sizeof(unsigned short);
    unsigned short* Wgz = (unsigned short*)p;  p += (size_t)H * H * sizeof(unsigned short);
    float* dinv = (float*)p;               p += (size_t)N * sizeof(float);
    float* rdeg = (float*)p;               p += (size_t)N * sizeof(float);
    int*   deg  = (int*)p;                 p += (size_t)N * sizeof(int);
    int*   offsets = (int*)p;              p += (size_t)(N + 1) * sizeof(int);
    int*   cursor  = (int*)p;              p += (size_t)N * sizeof(int);
    int*   chunkSum  = (int*)p;            p += (size_t)C * sizeof(int);
    int*   chunkBase = (int*)p;            p += (size_t)C * sizeof(int);
    int*   adj  = (int*)p;                 p += (size_t)E * sizeof(int);

    hipMemsetAsync(deg, 0, (size_t)N * sizeof(int), stream);

    k_deg<<<(E + 255) / 256, 256, 0, stream>>>(ei + E, E, deg);
    k_dinv<<<(N + 255) / 256, 256, 0, stream>>>(deg, N, dinv, rdeg);
    k_chunksum<<<C, 256, 0, stream>>>(deg, N, chunkSum);
    k_chunkscan<<<1, 64, 0, stream>>>(chunkSum, C, chunkBase, offsets, N);
    k_localscan<<<C, 256, 0, stream>>>(deg, N, chunkBase, offsets, cursor);
    k_fill<<<(E + 255) / 256, 256, 0, stream>>>(ei, E, cursor, adj);
    k_weff_bf<<<(H * H + 255) / 256, 256, 0, stream>>>(msg_W, msg_A, msg_B, Wmz);
    k_weff_bf<<<(H * H + 255) / 256, 256, 0, stream>>>(gate_W, gate_A, gate_B, Wgz);
    // mean-divided messages land in d_out
    k_gather<<<((size_t)N * 64 + 255) / 256, 256, 0, stream>>>(
        (const float2*)hidden, offsets, adj, dinv, rdeg, N, (float2*)out);
    int waves = (N + 15) / 16;
    k_fused<<<(waves + 3) / 4, 256, 0, stream>>>(
        hidden, out, Wmz, Wgz, msg_b, gate_b, gamma, beta, out, N);
}